// Round 22
// baseline (153.993 us; speedup 1.0000x reference)
//
#include <hip/hip_runtime.h>
#include <hip/hip_bf16.h>
#include <hip/hip_cooperative_groups.h>

namespace cg = cooperative_groups;

#define B_ 8192
#define C_ 10000
#define D_ 128
#define CPAD 10112      // 158 * 64
#define NPADC 112       // CPAD - C_
#define NT_TOT 158      // 64-col tiles
#define NSTRIP 16
#define STRIPW 10       // strips 0..14 -> 10 tiles, strip 15 -> 8 (even)

typedef float f32x4 __attribute__((ext_vector_type(4)));
typedef int   i32x8 __attribute__((ext_vector_type(8)));

// ---------------- ws layout (float offsets) ----------------
// counts    : [0, 10240)
// sumx      : [10240, 1290240)
// git_row   : [1290240, 1298432)
// xnorm     : [1298432, 1306624)
// cent_val  : [1306624, 1314816)
// cnorm     : [1314816, 1325056)   (CPAD, pad = 0)
// x_fp4     : byte 5,300,224  (8192 x 64B = 512 KB)
// c_fp4     : byte 7,397,376  (CPAD x 64B = 632 KB, pad rows zero)

// float -> e2m1 code (grid 0,.5,1,1.5,2,3,4,6; RTN)
__device__ inline unsigned fp4q(float v) {
    float m = fabsf(v);
    unsigned s = (__float_as_uint(v) >> 31) << 3;
    unsigned c;
    if      (m < 0.25f) c = 0;
    else if (m < 0.75f) c = 1;
    else if (m < 1.25f) c = 2;
    else if (m < 1.75f) c = 3;
    else if (m < 2.5f)  c = 4;
    else if (m < 3.5f)  c = 5;
    else if (m < 5.0f)  c = 6;
    else                c = 7;
    return s | c;
}

// ONE cooperative kernel: phase1 zero, phase2 scatter+fp4+xnorm,
// phase3 center-update + exact labeled distances. 512 blocks x 256 thr
// (2 blocks/CU -> co-residency guaranteed); two grid.sync()s.
__global__ void __launch_bounds__(256)
fused_pre(const float* __restrict__ x, const int* __restrict__ labels,
          const float* __restrict__ centers, const float* __restrict__ lr,
          float* __restrict__ counts, float* __restrict__ sumx,
          float* __restrict__ xnorm, float* __restrict__ cnorm,
          unsigned char* __restrict__ xb4, unsigned char* __restrict__ cb4,
          float* __restrict__ cent_val, float* __restrict__ out) {
    cg::grid_group grid = cg::this_grid();
    int tid = threadIdx.x;
    int bid = blockIdx.x;             // 0..511
    int gidx = bid * 256 + tid;       // 0..131071
    int w = tid >> 6, lane = tid & 63;
    int wgid = bid * 4 + w;           // 0..2047 (global wave id)

    // ---- phase 1: zero counts+sumx+git_row (324,608 float4) + out ----
    float4* wz = (float4*)counts;     // counts is ws base
    #pragma unroll
    for (int p = 0; p < 3; p++) {
        int i = gidx + p * 131072;
        if (i < 324608) wz[i] = float4{0.f, 0.f, 0.f, 0.f};
    }
    if (gidx == 0) { out[0] = 0.f; out[1] = 0.f; }
    grid.sync();

    // ---- phase 2: scatter segment-sums + fp4 cast + xnorm (4 rows/wave) ----
    #pragma unroll
    for (int r = 0; r < 4; r++) {
        int i = wgid + r * 2048;      // 0..8191
        int l = labels[i];
        float2 v = *(const float2*)&x[i * D_ + lane * 2];
        atomicAdd(&sumx[l * D_ + lane * 2], v.x);
        atomicAdd(&sumx[l * D_ + lane * 2 + 1], v.y);
        if (lane == 0) atomicAdd(&counts[l], 1.0f);
        xb4[i * 64 + lane] = (unsigned char)(fp4q(v.x) | (fp4q(v.y) << 4));
        float s = v.x * v.x + v.y * v.y;
        #pragma unroll
        for (int m = 1; m < 64; m <<= 1) s += __shfl_xor(s, m);
        if (lane == 0) xnorm[i] = s;
    }
    grid.sync();

    // ---- phase 3: center update (CPAD=10112 units) + cvals (8192 units) ----
    float lrv = lr[0];
    for (int u = 0; u < 9; u++) {
        int unit = wgid + u * 2048;   // 0..18431
        if (unit < CPAD) {
            int c = unit;
            if (c >= C_) {
                cb4[c * 64 + lane] = 0;
                if (lane == 0) cnorm[c] = 0.0f;
                continue;
            }
            float cnt = counts[c];
            float2 cv = *(const float2*)&centers[c * D_ + lane * 2];
            float2 sx = *(const float2*)&sumx[c * D_ + lane * 2];
            float inv = 1.0f / (1.0f + cnt);
            float nx = cv.x - lrv * (cnt * cv.x - sx.x) * inv;
            float ny = cv.y - lrv * (cnt * cv.y - sx.y) * inv;
            cb4[c * 64 + lane] = (unsigned char)(fp4q(nx) | (fp4q(ny) << 4));
            float s = nx * nx + ny * ny;
            #pragma unroll
            for (int m = 1; m < 64; m <<= 1) s += __shfl_xor(s, m);
            if (lane == 0) cnorm[c] = s;
        } else if (unit < CPAD + B_) {
            int i = unit - CPAD;
            int l = labels[i];
            float cnt = counts[l];
            float inv = 1.0f / (1.0f + cnt);
            float2 a  = *(const float2*)&x[i * D_ + lane * 2];
            float2 cv = *(const float2*)&centers[l * D_ + lane * 2];
            float2 sx = *(const float2*)&sumx[l * D_ + lane * 2];
            float nx = cv.x - lrv * (cnt * cv.x - sx.x) * inv;
            float ny = cv.y - lrv * (cnt * cv.y - sx.y) * inv;
            float dx = a.x - nx, dy = a.y - ny;
            float s = dx * dx + dy * dy;
            #pragma unroll
            for (int m = 1; m < 64; m <<= 1) s += __shfl_xor(s, m);
            if (lane == 0) cent_val[i] = s;
        }
    }
}

// Barrier-free MX-FP4 GEMM + git (byte-identical to R21 best).
__global__ void __launch_bounds__(256, 2)
gemm_git(const unsigned char* __restrict__ xb4, const unsigned char* __restrict__ cb4,
         const float* __restrict__ xnorm, const float* __restrict__ cnorm,
         float* __restrict__ git_row) {
    int tid = threadIdx.x;
    int w = tid >> 6, lane = tid & 63;
    int lr_ = lane & 15, lg = lane >> 4;
    int bm = blockIdx.x;              // 0..31
    int strip = blockIdx.y;           // 0..15
    int row0 = bm * 256 + w * 64;
    int bn0 = strip * STRIPW;
    int nt = (strip == NSTRIP - 1) ? (NT_TOT - bn0) : STRIPW;

    i32x8 af[4];
    #pragma unroll
    for (int f = 0; f < 4; f++) {
        const uint4* pa = (const uint4*)(xb4 + (size_t)(row0 + f * 16 + lr_) * 64 + lg * 16);
        uint4 u0 = pa[0];
        asm volatile("" : "+v"(u0.x), "+v"(u0.y), "+v"(u0.z), "+v"(u0.w));
        af[f] = i32x8{(int)u0.x, (int)u0.y, (int)u0.z, (int)u0.w, 0, 0, 0, 0};
    }

    float xn1[4][4];
    #pragma unroll
    for (int fm = 0; fm < 4; fm++)
        #pragma unroll
        for (int r = 0; r < 4; r++) {
            float v = 1.0f + xnorm[row0 + fm * 16 + lg * 4 + r];
            asm volatile("" : "+v"(v));
            xn1[fm][r] = v;
        }

    float gitsum[4][4] = {};

    i32x8 b0[4], b1[4];
    float c0[4], c1[4];

    auto loadB = [&](int t, i32x8 bf[4], float cn[4]) {
        int cb0 = (bn0 + t) * 64;
        #pragma unroll
        for (int fn = 0; fn < 4; fn++) {
            const uint4* pb = (const uint4*)(cb4 + (size_t)(cb0 + fn * 16 + lr_) * 64 + lg * 16);
            uint4 q = pb[0];
            bf[fn] = i32x8{(int)q.x, (int)q.y, (int)q.z, (int)q.w, 0, 0, 0, 0};
        }
        #pragma unroll
        for (int fn = 0; fn < 4; fn++) cn[fn] = cnorm[(bn0 + t) * 64 + fn * 16 + lr_];
    };

    auto compute = [&](const i32x8 bf[4], const float cn[4]) {
        f32x4 acc[4][4] = {};
        #pragma unroll
        for (int fm = 0; fm < 4; fm++)
            #pragma unroll
            for (int fn = 0; fn < 4; fn++)
                acc[fm][fn] = __builtin_amdgcn_mfma_scale_f32_16x16x128_f8f6f4(
                    af[fm], bf[fn], acc[fm][fn],
                    4, 4,             // cbsz=fp4(e2m1), blgp=fp4(e2m1)
                    0, 0x7F,          // scale_a opsel, scale_a (e8m0 1.0)
                    0, 0x7F);         // scale_b opsel, scale_b
        #pragma unroll
        for (int fm = 0; fm < 4; fm++)
            #pragma unroll
            for (int r = 0; r < 4; r++) {
                float base = xn1[fm][r];
                #pragma unroll
                for (int fp = 0; fp < 4; fp += 2) {
                    float u = base + cn[fp]     - 2.0f * acc[fm][fp][r];
                    float v = base + cn[fp + 1] - 2.0f * acc[fm][fp + 1][r];
                    gitsum[fm][r] += (u + v) * __builtin_amdgcn_rcpf(u * v);
                }
            }
    };

    loadB(0, b0, c0);
    for (int t = 0; t < nt; t += 2) {       // nt is even (10 or 8)
        if (t + 1 < nt) loadB(t + 1, b1, c1);
        compute(b0, c0);
        if (t + 2 < nt) loadB(t + 2, b0, c0);
        compute(b1, c1);
    }

    #pragma unroll
    for (int fm = 0; fm < 4; fm++)
        #pragma unroll
        for (int r = 0; r < 4; r++) {
            float s = gitsum[fm][r];
            s += __shfl_xor(s, 1); s += __shfl_xor(s, 2);
            s += __shfl_xor(s, 4); s += __shfl_xor(s, 8);
            if (lr_ == 0) atomicAdd(&git_row[row0 + fm * 16 + lg * 4 + r], s);
        }
}

__global__ void final_reduce(const float* __restrict__ cent_val, const float* __restrict__ git_row,
                             const float* __restrict__ xnorm, float* __restrict__ out) {
    int tid = threadIdx.x;
    int i = blockIdx.x * 256 + tid;
    float c = cent_val[i];
    float cl = fminf(fmaxf(c, 1e-12f), 1e12f);
    float g = git_row[i] - 1.0f / (1.0f + c) - (float)NPADC / (1.0f + xnorm[i]);
    float gl = fminf(fmaxf(g, 1e-12f), 1e12f);
    #pragma unroll
    for (int m = 1; m < 64; m <<= 1) { cl += __shfl_xor(cl, m); gl += __shfl_xor(gl, m); }
    __shared__ float scl[4], sgl[4];
    if ((tid & 63) == 0) { scl[tid >> 6] = cl; sgl[tid >> 6] = gl; }
    __syncthreads();
    if (tid == 0) {
        float a = scl[0] + scl[1] + scl[2] + scl[3];
        float b = sgl[0] + sgl[1] + sgl[2] + sgl[3];
        atomicAdd(&out[0], a / (float)B_);
        atomicAdd(&out[1], b / (float)B_);
    }
}

extern "C" void kernel_launch(void* const* d_in, const int* in_sizes, int n_in,
                              void* d_out, int out_size, void* d_ws, size_t ws_size,
                              hipStream_t stream) {
    const float* x       = (const float*)d_in[0];
    const int*   labels  = (const int*)d_in[1];
    const float* centers = (const float*)d_in[2];
    const float* lr      = (const float*)d_in[3];

    float* ws       = (float*)d_ws;
    float* counts   = ws;
    float* sumx     = ws + 10240;
    float* git_row  = ws + 1290240;
    float* xnorm    = ws + 1298432;
    float* cent_val = ws + 1306624;
    float* cnorm    = ws + 1314816;
    unsigned char* xb4 = (unsigned char*)d_ws + 5300224;
    unsigned char* cb4 = (unsigned char*)d_ws + 7397376;
    float* out = (float*)d_out;

    void* args[] = { (void*)&x, (void*)&labels, (void*)&centers, (void*)&lr,
                     (void*)&counts, (void*)&sumx, (void*)&xnorm, (void*)&cnorm,
                     (void*)&xb4, (void*)&cb4, (void*)&cent_val, (void*)&out };
    hipLaunchCooperativeKernel((const void*)fused_pre, dim3(512), dim3(256),
                               args, 0, stream);
    gemm_git<<<dim3(32, NSTRIP), 256, 0, stream>>>(xb4, cb4, xnorm, cnorm, git_row);
    final_reduce<<<32, 256, 0, stream>>>(cent_val, git_row, xnorm, out);
}

// Round 23
// 46.404 us; speedup vs baseline: 3.3185x; 3.3185x over previous
//
#include <hip/hip_runtime.h>
#include <hip/hip_bf16.h>

#define B_ 8192
#define C_ 10000
#define D_ 128
#define CPAD 10112      // 158 * 64
#define NPADC 112       // CPAD - C_
#define NT_TOT 158      // 64-col tiles
#define NSTRIP 16
#define STRIPW 10       // strips 0..14 -> 10 tiles, strip 15 -> 8 (even)
#define UPD_BLOCKS 2528 // CPAD/4
#define CVAL_BLOCKS 2048// B_/4

typedef float f32x4 __attribute__((ext_vector_type(4)));
typedef int   i32x8 __attribute__((ext_vector_type(8)));

// ---------------- ws layout (float offsets) ----------------
// counts    : [0, 10240)
// sumx      : [10240, 1290240)
// git_row   : [1290240, 1298432)
// xnorm     : [1298432, 1306624)
// cent_val  : [1306624, 1314816)
// cnorm     : [1314816, 1325056)   (CPAD, pad = 0)
// x_fp4     : byte 5,300,224  (8192 x 64B = 512 KB)
// c_fp4     : byte 7,397,376  (CPAD x 64B = 632 KB, pad rows zero)

// float -> e2m1 code (grid 0,.5,1,1.5,2,3,4,6; RTN)
__device__ inline unsigned fp4q(float v) {
    float m = fabsf(v);
    unsigned s = (__float_as_uint(v) >> 31) << 3;
    unsigned c;
    if      (m < 0.25f) c = 0;
    else if (m < 0.75f) c = 1;
    else if (m < 1.25f) c = 2;
    else if (m < 1.75f) c = 3;
    else if (m < 2.5f)  c = 4;
    else if (m < 3.5f)  c = 5;
    else if (m < 5.0f)  c = 6;
    else                c = 7;
    return s | c;
}

__global__ void zero_ws(float4* __restrict__ ws, float* __restrict__ out) {
    int idx = blockIdx.x * 256 + threadIdx.x;
    if (idx < 324608) ws[idx] = float4{0.f, 0.f, 0.f, 0.f};
    if (idx == 0) { out[0] = 0.f; out[1] = 0.f; }
}

// Fused: segment-sum atomics + fp4 cast + xnorm (single pass over x).
__global__ void scatter_prep(const float* __restrict__ x, const int* __restrict__ labels,
                             float* __restrict__ counts, float* __restrict__ sumx,
                             float* __restrict__ xnorm, unsigned char* __restrict__ xb4) {
    int tid = threadIdx.x;
    int w = tid >> 6, lane = tid & 63;
    int i = blockIdx.x * 4 + w;
    int l = labels[i];
    float2 v = *(const float2*)&x[i * D_ + lane * 2];
    atomicAdd(&sumx[l * D_ + lane * 2], v.x);
    atomicAdd(&sumx[l * D_ + lane * 2 + 1], v.y);
    if (lane == 0) atomicAdd(&counts[l], 1.0f);
    xb4[i * 64 + lane] = (unsigned char)(fp4q(v.x) | (fp4q(v.y) << 4));
    float s = v.x * v.x + v.y * v.y;
    #pragma unroll
    for (int m = 1; m < 64; m <<= 1) s += __shfl_xor(s, m);
    if (lane == 0) xnorm[i] = s;
}

__global__ void upd_cvals(const float* __restrict__ centers, const float* __restrict__ counts,
                          const float* __restrict__ sumx, float* __restrict__ cnorm,
                          unsigned char* __restrict__ cb4, const float* __restrict__ lr,
                          const float* __restrict__ x, const int* __restrict__ labels,
                          float* __restrict__ cent_val) {
    int tid = threadIdx.x;
    int w = tid >> 6, lane = tid & 63;
    int bid = blockIdx.x;
    float lrv = lr[0];

    if (bid < UPD_BLOCKS) {
        int c = bid * 4 + w;
        if (c >= C_) {
            cb4[c * 64 + lane] = 0;
            if (lane == 0) cnorm[c] = 0.0f;
            return;
        }
        float cnt = counts[c];
        float2 cv = *(const float2*)&centers[c * D_ + lane * 2];
        float2 sx = *(const float2*)&sumx[c * D_ + lane * 2];
        float inv = 1.0f / (1.0f + cnt);
        float nx = cv.x - lrv * (cnt * cv.x - sx.x) * inv;
        float ny = cv.y - lrv * (cnt * cv.y - sx.y) * inv;
        cb4[c * 64 + lane] = (unsigned char)(fp4q(nx) | (fp4q(ny) << 4));
        float s = nx * nx + ny * ny;
        #pragma unroll
        for (int m = 1; m < 64; m <<= 1) s += __shfl_xor(s, m);
        if (lane == 0) cnorm[c] = s;
    } else {
        int i = (bid - UPD_BLOCKS) * 4 + w;
        int l = labels[i];
        float cnt = counts[l];
        float inv = 1.0f / (1.0f + cnt);
        float2 a  = *(const float2*)&x[i * D_ + lane * 2];
        float2 cv = *(const float2*)&centers[l * D_ + lane * 2];
        float2 sx = *(const float2*)&sumx[l * D_ + lane * 2];
        float nx = cv.x - lrv * (cnt * cv.x - sx.x) * inv;
        float ny = cv.y - lrv * (cnt * cv.y - sx.y) * inv;
        float dx = a.x - nx, dy = a.y - ny;
        float s = dx * dx + dy * dy;
        #pragma unroll
        for (int m = 1; m < 64; m <<= 1) s += __shfl_xor(s, m);
        if (lane == 0) cent_val[i] = s;
    }
}

// Barrier-free MX-FP4 GEMM + git: NO LDS, NO syncthreads. Each wave marches
// its strip independently; B fragments double-buffered in NAMED register
// sets; B tile = 4KB, L1-resident across the block's 8 waves.
__global__ void __launch_bounds__(256, 2)
gemm_git(const unsigned char* __restrict__ xb4, const unsigned char* __restrict__ cb4,
         const float* __restrict__ xnorm, const float* __restrict__ cnorm,
         float* __restrict__ git_row) {
    int tid = threadIdx.x;
    int w = tid >> 6, lane = tid & 63;
    int lr_ = lane & 15, lg = lane >> 4;
    int bm = blockIdx.x;              // 0..31
    int strip = blockIdx.y;           // 0..15
    int row0 = bm * 256 + w * 64;
    int bn0 = strip * STRIPW;
    int nt = (strip == NSTRIP - 1) ? (NT_TOT - bn0) : STRIPW;

    // A fragments: lane holds row (row0+f*16+lr_), 16B at offset lg*16; pinned.
    i32x8 af[4];
    #pragma unroll
    for (int f = 0; f < 4; f++) {
        const uint4* pa = (const uint4*)(xb4 + (size_t)(row0 + f * 16 + lr_) * 64 + lg * 16);
        uint4 u0 = pa[0];
        asm volatile("" : "+v"(u0.x), "+v"(u0.y), "+v"(u0.z), "+v"(u0.w));
        af[f] = i32x8{(int)u0.x, (int)u0.y, (int)u0.z, (int)u0.w, 0, 0, 0, 0};
    }

    float xn1[4][4];
    #pragma unroll
    for (int fm = 0; fm < 4; fm++)
        #pragma unroll
        for (int r = 0; r < 4; r++) {
            float v = 1.0f + xnorm[row0 + fm * 16 + lg * 4 + r];
            asm volatile("" : "+v"(v));
            xn1[fm][r] = v;
        }

    float gitsum[4][4] = {};

    i32x8 b0[4], b1[4];
    float c0[4], c1[4];

    auto loadB = [&](int t, i32x8 bf[4], float cn[4]) {
        int cb0 = (bn0 + t) * 64;
        #pragma unroll
        for (int fn = 0; fn < 4; fn++) {
            const uint4* pb = (const uint4*)(cb4 + (size_t)(cb0 + fn * 16 + lr_) * 64 + lg * 16);
            uint4 q = pb[0];
            bf[fn] = i32x8{(int)q.x, (int)q.y, (int)q.z, (int)q.w, 0, 0, 0, 0};
        }
        #pragma unroll
        for (int fn = 0; fn < 4; fn++) cn[fn] = cnorm[(bn0 + t) * 64 + fn * 16 + lr_];
    };

    auto compute = [&](const i32x8 bf[4], const float cn[4]) {
        f32x4 acc[4][4] = {};
        #pragma unroll
        for (int fm = 0; fm < 4; fm++)
            #pragma unroll
            for (int fn = 0; fn < 4; fn++)
                acc[fm][fn] = __builtin_amdgcn_mfma_scale_f32_16x16x128_f8f6f4(
                    af[fm], bf[fn], acc[fm][fn],
                    4, 4,             // cbsz=fp4(e2m1), blgp=fp4(e2m1)
                    0, 0x7F,          // scale_a opsel, scale_a (e8m0 1.0)
                    0, 0x7F);         // scale_b opsel, scale_b
        #pragma unroll
        for (int fm = 0; fm < 4; fm++)
            #pragma unroll
            for (int r = 0; r < 4; r++) {
                float base = xn1[fm][r];
                #pragma unroll
                for (int fp = 0; fp < 4; fp += 2) {
                    float u = base + cn[fp]     - 2.0f * acc[fm][fp][r];
                    float v = base + cn[fp + 1] - 2.0f * acc[fm][fp + 1][r];
                    gitsum[fm][r] += (u + v) * __builtin_amdgcn_rcpf(u * v);
                }
            }
    };

    loadB(0, b0, c0);
    for (int t = 0; t < nt; t += 2) {       // nt is even (10 or 8)
        if (t + 1 < nt) loadB(t + 1, b1, c1);
        compute(b0, c0);
        if (t + 2 < nt) loadB(t + 2, b0, c0);
        compute(b1, c1);
    }

    #pragma unroll
    for (int fm = 0; fm < 4; fm++)
        #pragma unroll
        for (int r = 0; r < 4; r++) {
            float s = gitsum[fm][r];
            s += __shfl_xor(s, 1); s += __shfl_xor(s, 2);
            s += __shfl_xor(s, 4); s += __shfl_xor(s, 8);
            if (lr_ == 0) atomicAdd(&git_row[row0 + fm * 16 + lg * 4 + r], s);
        }
}

__global__ void final_reduce(const float* __restrict__ cent_val, const float* __restrict__ git_row,
                             const float* __restrict__ xnorm, float* __restrict__ out) {
    int tid = threadIdx.x;
    int i = blockIdx.x * 256 + tid;
    float c = cent_val[i];
    float cl = fminf(fmaxf(c, 1e-12f), 1e12f);
    float g = git_row[i] - 1.0f / (1.0f + c) - (float)NPADC / (1.0f + xnorm[i]);
    float gl = fminf(fmaxf(g, 1e-12f), 1e12f);
    #pragma unroll
    for (int m = 1; m < 64; m <<= 1) { cl += __shfl_xor(cl, m); gl += __shfl_xor(gl, m); }
    __shared__ float scl[4], sgl[4];
    if ((tid & 63) == 0) { scl[tid >> 6] = cl; sgl[tid >> 6] = gl; }
    __syncthreads();
    if (tid == 0) {
        float a = scl[0] + scl[1] + scl[2] + scl[3];
        float b = sgl[0] + sgl[1] + sgl[2] + sgl[3];
        atomicAdd(&out[0], a / (float)B_);
        atomicAdd(&out[1], b / (float)B_);
    }
}

extern "C" void kernel_launch(void* const* d_in, const int* in_sizes, int n_in,
                              void* d_out, int out_size, void* d_ws, size_t ws_size,
                              hipStream_t stream) {
    const float* x       = (const float*)d_in[0];
    const int*   labels  = (const int*)d_in[1];
    const float* centers = (const float*)d_in[2];
    const float* lr      = (const float*)d_in[3];

    float* ws       = (float*)d_ws;
    float* counts   = ws;
    float* sumx     = ws + 10240;
    float* git_row  = ws + 1290240;
    float* xnorm    = ws + 1298432;
    float* cent_val = ws + 1306624;
    float* cnorm    = ws + 1314816;
    unsigned char* xb4 = (unsigned char*)d_ws + 5300224;
    unsigned char* cb4 = (unsigned char*)d_ws + 7397376;
    float* out = (float*)d_out;

    zero_ws<<<1268, 256, 0, stream>>>((float4*)d_ws, out);
    scatter_prep<<<B_ / 4, 256, 0, stream>>>(x, labels, counts, sumx, xnorm, xb4);
    upd_cvals<<<UPD_BLOCKS + CVAL_BLOCKS, 256, 0, stream>>>(centers, counts, sumx, cnorm, cb4, lr,
                                                            x, labels, cent_val);
    gemm_git<<<dim3(32, NSTRIP), 256, 0, stream>>>(xb4, cb4, xnorm, cnorm, git_row);
    final_reduce<<<32, 256, 0, stream>>>(cent_val, git_row, xnorm, out);
}